// Round 2
// baseline (3145.052 us; speedup 1.0000x reference)
//
#include <hip/hip_runtime.h>
#include <hip/hip_fp16.h>

#define B_ 16
#define T_ 65536
#define H_ 64
#define N_ 64
#define DEPTH_ 4
#define CHUNK 256
#define NCH (T_ / CHUNK)   // 256 chunks per sequence

// ---------- helpers ----------
__device__ __forceinline__ float ldc(const float* p) { return *p; }

__device__ __forceinline__ void load4f(const float* p, float* f) {
    float4 v = *(const float4*)p;
    f[0] = v.x; f[1] = v.y; f[2] = v.z; f[3] = v.w;
}
__device__ __forceinline__ void load4f(const __half* p, float* f) {
    ushort4 v = *(const ushort4*)p;
    f[0] = __half2float(__ushort_as_half(v.x));
    f[1] = __half2float(__ushort_as_half(v.y));
    f[2] = __half2float(__ushort_as_half(v.z));
    f[3] = __half2float(__ushort_as_half(v.w));
}
__device__ __forceinline__ void st1(float* p, float v) { *p = v; }
__device__ __forceinline__ void st1(__half* p, float v) { *p = __float2half(v); }

// ---------- pass 1: per-chunk carry  s_c = sum_j A^{L-1-j} * Bu_j ----------
// IN_X=1: layer-0 input u_t = x_t * Win  =>  Bu_t[n] = x_t * g[n] * (Bm[n]·Win)
template<int IN_X, typename UT>
__global__ __launch_bounds__(64)
void lru_pass1(const float* __restrict__ x,
               const UT* __restrict__ hbuf,
               const float* __restrict__ Win,
               const float* __restrict__ nu_log,
               const float* __restrict__ gamma_log,
               const float* __restrict__ Bm,
               float* __restrict__ carry)
{
    const int blk = blockIdx.x;
    const int b = blk >> 8;            // / NCH
    const int c = blk & (NCH - 1);
    const int n = threadIdx.x;
    const int t0 = c * CHUNK;

    const float ex = expf(ldc(nu_log + n));
    const float a  = expf(-ex);
    const float g  = expf(ldc(gamma_log + n));
    float s = 0.f;

    if (IN_X) {
        float bw = 0.f;
        #pragma unroll
        for (int h = 0; h < H_; ++h)
            bw += ldc(Bm + n * H_ + h) * ldc(Win + h);
        bw *= g;
        __shared__ float xs[64];
        const float* xp = x + (size_t)b * T_ + t0;
        for (int bb = 0; bb < CHUNK / 64; ++bb) {
            __syncthreads();
            xs[n] = xp[bb * 64 + n];
            __syncthreads();
            #pragma unroll
            for (int tt = 0; tt < 64; ++tt)
                s = a * s + bw * xs[tt];
        }
    } else {
        float bmr[H_];
        #pragma unroll
        for (int h = 0; h < H_; ++h)
            bmr[h] = g * ldc(Bm + n * H_ + h);

        __shared__ float ush[2][256];   // 4 timesteps x 64 features, double buffered
        const UT* up = hbuf + ((size_t)b * T_ + t0) * H_;
        float pf[4];
        load4f(up + n * 4, pf);
        ((float4*)ush[0])[n] = make_float4(pf[0], pf[1], pf[2], pf[3]);

        const int NB = CHUNK / 4;
        for (int tb = 0; tb < NB; ++tb) {
            const int cur = tb & 1;
            if (tb + 1 < NB) load4f(up + (size_t)(tb + 1) * 256 + n * 4, pf);
            __syncthreads();
            #pragma unroll
            for (int tt = 0; tt < 4; ++tt) {
                float bu = 0.f;
                #pragma unroll
                for (int h = 0; h < H_; ++h)
                    bu += bmr[h] * ush[cur][tt * 64 + h];   // broadcast reads
                s = a * s + bu;
            }
            if (tb + 1 < NB)
                ((float4*)ush[cur ^ 1])[n] = make_float4(pf[0], pf[1], pf[2], pf[3]);
        }
    }
    carry[((size_t)b * NCH + c) * N_ + n] = s;
}

// ---------- pass 3: chunk-start state (from carries) + sequential chunk walk ----------
// wave0: Bu + state update; wave1: y = Cm·h_prev + Dv*u, tanh; wave2: Wlin·th + blin + u (lagged 1 step)
template<int IN_X, int OUT_FINAL, typename UT>
__global__ __launch_bounds__(192)
void lru_pass3(const float* __restrict__ x,
               UT* hbuf,
               const float* __restrict__ Win,
               const float* __restrict__ nu_log,
               const float* __restrict__ gamma_log,
               const float* __restrict__ Bm,
               const float* __restrict__ Cm,
               const float* __restrict__ Dv,
               const float* __restrict__ Wlin,
               const float* __restrict__ blin,
               const float* __restrict__ Wout,
               const float* __restrict__ carry,
               float* __restrict__ out)
{
    const int blk = blockIdx.x;
    const int b = blk >> 8;
    const int c = blk & (NCH - 1);
    const int t0 = c * CHUNK;
    const int tid = threadIdx.x;
    const int w = tid >> 6;            // wave id 0..2
    const int j = tid & 63;

    __shared__ float ush[2][256];      // u for 4 timesteps, fp32
    __shared__ float hsh[64];          // recurrent state h_{t-1}
    __shared__ float thsh[64];         // tanh(y) of previous step
    __shared__ float ursh[64];         // u of previous step (residual)

    float row[H_];
    float a = 0.f, dvj = 0.f, blj = 0.f, winj = 0.f, woj = 0.f;

    UT* hb = hbuf + ((size_t)b * T_ + t0) * H_;
    const float* xp = x + (size_t)b * T_ + t0;

    if (w == 0) {
        const float ex = expf(ldc(nu_log + j));
        a = expf(-ex);
        const float g = expf(ldc(gamma_log + j));
        #pragma unroll
        for (int h = 0; h < H_; ++h) row[h] = g * ldc(Bm + j * H_ + h);
        // chunk-start state: run over carries of chunks 0..c-1
        const float aL = expf(-ex * (float)CHUNK);
        const float* cp = carry + (size_t)b * NCH * N_ + j;
        float run = 0.f;
        int cc = 0;
        for (; cc + 8 <= c; cc += 8) {
            float v0 = cp[(cc + 0) * N_], v1 = cp[(cc + 1) * N_];
            float v2 = cp[(cc + 2) * N_], v3 = cp[(cc + 3) * N_];
            float v4 = cp[(cc + 4) * N_], v5 = cp[(cc + 5) * N_];
            float v6 = cp[(cc + 6) * N_], v7 = cp[(cc + 7) * N_];
            run = aL * run + v0; run = aL * run + v1; run = aL * run + v2; run = aL * run + v3;
            run = aL * run + v4; run = aL * run + v5; run = aL * run + v6; run = aL * run + v7;
        }
        for (; cc < c; ++cc) run = aL * run + cp[cc * N_];
        hsh[j] = run;
    } else if (w == 1) {
        #pragma unroll
        for (int h = 0; h < H_; ++h) row[h] = ldc(Cm + j * H_ + h);
        dvj = ldc(Dv + j);
    } else {
        #pragma unroll
        for (int h = 0; h < H_; ++h) row[h] = ldc(Wlin + j * H_ + h);
        blj = ldc(blin + j);
        if (OUT_FINAL) woj = ldc(Wout + j);
        if (IN_X) winj = ldc(Win + j);
    }

    // stage batch 0
    float pf[4];
    if (w == 2) {
        if (IN_X) {
            #pragma unroll
            for (int t2 = 0; t2 < 4; ++t2)
                ush[0][t2 * 64 + j] = xp[t2] * winj;   // xp[t2]: broadcast load
        } else {
            load4f((const UT*)hb + j * 4, pf);
            ((float4*)ush[0])[j] = make_float4(pf[0], pf[1], pf[2], pf[3]);
        }
    }
    __syncthreads();

    const int NB = CHUNK / 4;
    float pfx[4];
    for (int tb = 0; tb < NB; ++tb) {
        const int cur = tb & 1;
        if (w == 2 && tb + 1 < NB) {                  // prefetch next batch
            if (IN_X) {
                #pragma unroll
                for (int k = 0; k < 4; ++k) pfx[k] = xp[(tb + 1) * 4 + k];  // broadcast
            } else {
                load4f((const UT*)hb + (size_t)(tb + 1) * 256 + j * 4, pf);
            }
        }
        #pragma unroll
        for (int tt = 0; tt < 4; ++tt) {
            const int t = tb * 4 + tt;                // relative timestep
            float bu = 0.f, th = 0.f, uj = 0.f;
            if (w == 0) {
                #pragma unroll
                for (int h = 0; h < H_; ++h) bu += row[h] * ush[cur][tt * 64 + h];
            } else if (w == 1) {
                uj = ush[cur][tt * 64 + j];
                float yp = dvj * uj;
                #pragma unroll
                for (int h = 0; h < H_; ++h) yp += row[h] * hsh[h];
                th = yp * rsqrtf(1.f + yp * yp);
            } else if (t > 0) {                       // emit output for t-1
                float o = blj + ursh[j];
                #pragma unroll
                for (int h = 0; h < H_; ++h) o += row[h] * thsh[h];
                if (OUT_FINAL) {
                    float p = o * woj;
                    #pragma unroll
                    for (int off = 32; off >= 1; off >>= 1) p += __shfl_down(p, off);
                    if (j == 0) out[(size_t)b * T_ + t0 + t - 1] = p;
                } else {
                    st1(hb + (size_t)(t - 1) * H_ + j, o);
                }
            }
            __syncthreads();                          // phase A done (all reads of hsh/thsh/ursh)
            if (w == 0) {
                hsh[j] = a * hsh[j] + bu;
            } else if (w == 1) {
                thsh[j] = th;
                ursh[j] = uj;
            } else if (tt == 0 && tb + 1 < NB) {      // stage next u batch into free buffer
                if (IN_X) {
                    #pragma unroll
                    for (int t2 = 0; t2 < 4; ++t2)
                        ush[cur ^ 1][t2 * 64 + j] = pfx[t2] * winj;
                } else {
                    ((float4*)ush[cur ^ 1])[j] = make_float4(pf[0], pf[1], pf[2], pf[3]);
                }
            }
            __syncthreads();                          // phase B done
        }
    }
    // epilogue: output for relative t = CHUNK-1
    if (w == 2) {
        float o = blj + ursh[j];
        #pragma unroll
        for (int h = 0; h < H_; ++h) o += row[h] * thsh[h];
        if (OUT_FINAL) {
            float p = o * woj;
            #pragma unroll
            for (int off = 32; off >= 1; off >>= 1) p += __shfl_down(p, off);
            if (j == 0) out[(size_t)b * T_ + t0 + CHUNK - 1] = p;
        } else {
            st1(hb + (size_t)(CHUNK - 1) * H_ + j, o);
        }
    }
}

// ---------- host ----------
template<typename UT>
static void run_all(const float* x, const float* Win,
                    const float* nu, const float* ga,
                    const float* Bm, const float* Cm,
                    const float* Dv, const float* Wl,
                    const float* bl, const float* Wo,
                    UT* hbuf, float* carry, float* out, hipStream_t stream)
{
    dim3 grid(B_ * NCH), blk1(64), blk3(192);
    for (int i = 0; i < DEPTH_; ++i) {
        const float *nui = nu + i * N_, *gai = ga + i * N_;
        const float *Bmi = Bm + i * N_ * H_, *Cmi = Cm + i * H_ * N_;
        const float *Dvi = Dv + i * H_, *Wli = Wl + i * H_ * H_, *bli = bl + i * H_;
        if (i == 0)
            lru_pass1<1, UT><<<grid, blk1, 0, stream>>>(x, hbuf, Win, nui, gai, Bmi, carry);
        else
            lru_pass1<0, UT><<<grid, blk1, 0, stream>>>(x, hbuf, Win, nui, gai, Bmi, carry);
        if (i == 0)
            lru_pass3<1, 0, UT><<<grid, blk3, 0, stream>>>(x, hbuf, Win, nui, gai, Bmi, Cmi, Dvi, Wli, bli, Wo, carry, out);
        else if (i == DEPTH_ - 1)
            lru_pass3<0, 1, UT><<<grid, blk3, 0, stream>>>(x, hbuf, Win, nui, gai, Bmi, Cmi, Dvi, Wli, bli, Wo, carry, out);
        else
            lru_pass3<0, 0, UT><<<grid, blk3, 0, stream>>>(x, hbuf, Win, nui, gai, Bmi, Cmi, Dvi, Wli, bli, Wo, carry, out);
    }
}

extern "C" void kernel_launch(void* const* d_in, const int* in_sizes, int n_in,
                              void* d_out, int out_size, void* d_ws, size_t ws_size,
                              hipStream_t stream)
{
    const float* x   = (const float*)d_in[0];
    const float* Win = (const float*)d_in[1];
    const float* nu  = (const float*)d_in[2];
    const float* ga  = (const float*)d_in[3];
    const float* Bm  = (const float*)d_in[4];
    const float* Cm  = (const float*)d_in[5];
    const float* Dv  = (const float*)d_in[6];
    const float* Wl  = (const float*)d_in[7];
    const float* bl  = (const float*)d_in[8];
    const float* Wo  = (const float*)d_in[9];
    float* out = (float*)d_out;

    const size_t act = (size_t)B_ * T_ * H_;
    const size_t carry_bytes = (size_t)B_ * NCH * N_ * sizeof(float);

    if (ws_size >= act * sizeof(float) + carry_bytes) {
        float* hbuf  = (float*)d_ws;
        float* carry = (float*)((char*)d_ws + act * sizeof(float));
        run_all<float>(x, Win, nu, ga, Bm, Cm, Dv, Wl, bl, Wo, hbuf, carry, out, stream);
    } else {
        __half* hbuf = (__half*)d_ws;
        float* carry = (float*)((char*)d_ws + act * sizeof(__half));
        run_all<__half>(x, Win, nu, ga, Bm, Cm, Dv, Wl, bl, Wo, hbuf, carry, out, stream);
    }
}

// Round 4
// 2146.922 us; speedup vs baseline: 1.4649x; 1.4649x over previous
//
#include <hip/hip_runtime.h>

#define B_ 16
#define T_ 65536
#define H_ 64
#define DEPTH_ 4
#define CHUNK 128
#define NCH (T_ / CHUNK)   // 512 chunks per sequence

typedef _Float16 f16;
typedef f16 f16x8 __attribute__((ext_vector_type(8)));
typedef float f32x4 __attribute__((ext_vector_type(4)));

#define MFMA(a, b, c) __builtin_amdgcn_mfma_f32_16x16x32_f16(a, b, c, 0, 0, 0)
// swizzled word index into hpk: row t (0..127), word k (0..63)
#define SWZ(t, k) ((t) * 64 + ((k) ^ (((t) & 7) << 2)))

// ---------- pack/unpack f16 hi+lo pairs (eff ~2^-21 relative) ----------
__device__ __forceinline__ unsigned pack2(float s) {
    union { f16 h; unsigned short u; } a, b;
    a.h = (f16)s;
    float lo = s - (float)a.h;
    b.h = (f16)lo;
    return (unsigned)a.u | ((unsigned)b.u << 16);
}
__device__ __forceinline__ float unpk(unsigned w) {
    union { unsigned short u; f16 h; } a, b;
    a.u = (unsigned short)(w & 0xffff);
    b.u = (unsigned short)(w >> 16);
    return (float)a.h + (float)b.h;
}
__device__ __forceinline__ f16 hi_of(unsigned w) {
    union { unsigned short u; f16 h; } a; a.u = (unsigned short)(w & 0xffff); return a.h;
}
__device__ __forceinline__ f16 lo_of(unsigned w) {
    union { unsigned short u; f16 h; } a; a.u = (unsigned short)(w >> 16); return a.h;
}

// ---------- hi/lo fragment pairs ----------
struct frag2 { f16x8 hi, lo; };

__device__ __forceinline__ frag2 mk2(const float* p, float scale) {
    frag2 r;
    #pragma unroll
    for (int i = 0; i < 8; ++i) {
        float v = p[i] * scale;
        f16 h = (f16)v;
        r.hi[i] = h;
        r.lo[i] = (f16)(v - (float)h);
    }
    return r;
}
// A-frag (hi+lo) of u: lane holds row t, 8 consecutive k elements
__device__ __forceinline__ frag2 aload2(const float* up, long t, int k) {
    return mk2(up + t * 64 + k, 1.f);
}
__device__ __forceinline__ frag2 aload2(const f16* up, long t, int k) {
    frag2 r;
    r.hi = *(const f16x8*)(up + t * 64 + k);
    #pragma unroll
    for (int i = 0; i < 8; ++i) r.lo[i] = (f16)0.f;
    return r;
}
// B-frag pair from row-major weight W[ncol][k] (64x64 f32), scaled
__device__ __forceinline__ frag2 bfrag2(const float* W, int n, int k0, float scale) {
    return mk2(W + n * 64 + k0, scale);
}
// single-precision B-frag (for Wlin: |th|<=1 so f16 is plenty)
__device__ __forceinline__ f16x8 bfrag1(const float* W, int n, int k0) {
    const float* p = W + n * 64 + k0;
    f16x8 r;
    #pragma unroll
    for (int i = 0; i < 8; ++i) r[i] = (f16)p[i];
    return r;
}

// 3-term high-precision MFMA product: (Ah+Al)x(Bh+Bl) dropping Al*Bl
__device__ __forceinline__ f32x4 mfma3(const frag2& a, const frag2& b, f32x4 acc) {
    acc = MFMA(a.hi, b.hi, acc);
    acc = MFMA(a.lo, b.hi, acc);
    acc = MFMA(a.hi, b.lo, acc);
    return acc;
}

// ---------- carry kernel, layer 0 (u_t = x_t*Win, rank-1) ----------
__global__ __launch_bounds__(64)
void carry_x(const float* __restrict__ x,
             const float* __restrict__ Win,
             const float* __restrict__ nu_log,
             const float* __restrict__ gamma_log,
             const float* __restrict__ Bm,
             float* __restrict__ carry)
{
    const int blk = blockIdx.x;
    const int b = blk >> 9, c = blk & (NCH - 1);
    const int n = threadIdx.x;
    const int t0 = c * CHUNK;

    const float ex = expf(nu_log[n]);
    const float a  = expf(-ex);
    const float g  = expf(gamma_log[n]);
    float bw = 0.f;
    #pragma unroll
    for (int h = 0; h < 64; ++h) bw += Bm[n * 64 + h] * Win[h];
    bw *= g;

    __shared__ float xs[64];
    const float* xp = x + (size_t)b * T_ + t0;
    float s = 0.f;
    for (int bb = 0; bb < CHUNK / 64; ++bb) {
        __syncthreads();
        xs[n] = xp[bb * 64 + n];
        __syncthreads();
        #pragma unroll
        for (int tt = 0; tt < 64; ++tt) s = a * s + bw * xs[tt];
    }
    carry[((size_t)b * NCH + c) * 64 + n] = s;
}

// ---------- carry kernel, layers 1..3 (MFMA Bu + weighted reduce) ----------
template<typename UT>
__global__ __launch_bounds__(256, 2)
void carry_mfma(const UT* __restrict__ hbuf,
                const float* __restrict__ nu_log,
                const float* __restrict__ gamma_log,
                const float* __restrict__ Bm,
                float* __restrict__ carry)
{
    const int blk = blockIdx.x;
    const int b = blk >> 9, c = blk & (NCH - 1);
    const int t0 = c * CHUNK;
    const int tid = threadIdx.x;
    const int w = tid >> 6, lane = tid & 63;
    const int l15 = lane & 15, lq = lane >> 4;

    __shared__ float red[4][64];

    float exn[4];
    frag2 bf[4][2];
    #pragma unroll
    for (int nt = 0; nt < 4; ++nt) {
        int n = nt * 16 + l15;
        exn[nt] = expf(nu_log[n]);
        float g = expf(gamma_log[n]);
        bf[nt][0] = bfrag2(Bm, n, lq * 8,      g);
        bf[nt][1] = bfrag2(Bm, n, 32 + lq * 8, g);
    }

    const UT* up = hbuf + ((size_t)b * T_ + t0) * 64;
    float partial[4] = {0.f, 0.f, 0.f, 0.f};

    #pragma unroll
    for (int tt = 0; tt < 2; ++tt) {
        int tb = 2 * w + tt;
        frag2 a0 = aload2(up, tb * 16 + l15, lq * 8);
        frag2 a1 = aload2(up, tb * 16 + l15, 32 + lq * 8);
        #pragma unroll
        for (int nt = 0; nt < 4; ++nt) {
            f32x4 acc = {0.f, 0.f, 0.f, 0.f};
            acc = mfma3(a0, bf[nt][0], acc);
            acc = mfma3(a1, bf[nt][1], acc);
            #pragma unroll
            for (int r = 0; r < 4; ++r) {
                int t = tb * 16 + lq * 4 + r;
                partial[nt] += expf(-exn[nt] * (float)(CHUNK - 1 - t)) * acc[r];
            }
        }
    }
    #pragma unroll
    for (int nt = 0; nt < 4; ++nt) {
        float v = partial[nt];
        v += __shfl_xor(v, 16);
        v += __shfl_xor(v, 32);
        if (lq == 0) red[w][nt * 16 + l15] = v;
    }
    __syncthreads();
    if (w == 0) {
        float s = red[0][lane] + red[1][lane] + red[2][lane] + red[3][lane];
        carry[((size_t)b * NCH + c) * 64 + lane] = s;
    }
}

// ---------- fused chunk kernel: carry-prefix + Bu GEMM + scan + C GEMM + tanh + Wlin GEMM ----------
template<int IN_X, int OUT_FINAL, typename UT>
__global__ __launch_bounds__(256, 2)
void lru_mfma(const float* __restrict__ x,
              UT* hbuf,
              const float* __restrict__ Win,
              const float* __restrict__ nu_log,
              const float* __restrict__ gamma_log,
              const float* __restrict__ Bm,
              const float* __restrict__ Cm,
              const float* __restrict__ Dv,
              const float* __restrict__ Wlin,
              const float* __restrict__ blin,
              const float* __restrict__ Wout,
              const float* __restrict__ carry,
              float* __restrict__ out)
{
    const int blk = blockIdx.x;
    const int b = blk >> 9, c = blk & (NCH - 1);
    const int t0 = c * CHUNK;
    const int tid = threadIdx.x;
    const int w = tid >> 6, lane = tid & 63;
    const int l15 = lane & 15, lq = lane >> 4;

    __shared__ float buf[CHUNK * 65];          // Bu fp32 (row stride 65); later th as f16 rows stride 72
    __shared__ unsigned hpk[CHUNK * 64];       // packed h hi/lo; hpk[t] = h_{t-1}
    __shared__ float swv[4][64];
    __shared__ float hst[64];

    const float ex_n = expf(nu_log[lane]);     // per-lane n = lane (for scan)
    const float a_n  = expf(-ex_n);

    UT* ug = hbuf + ((size_t)b * T_ + t0) * 64;
    const float* xg = x + (size_t)b * T_ + t0;

    // ---- P0a: partial carry-prefix (4-way split over chunks 0..c-1) ----
    {
        const float aL = expf(-ex_n * (float)CHUNK);
        int q = (c + 3) >> 2;
        int lo = w * q; if (lo > c) lo = c;
        int hi = lo + q; if (hi > c) hi = c;
        float p = 0.f;
        const float* cp = carry + (size_t)b * NCH * 64 + lane;
        for (int cc = lo; cc < hi; ++cc) p = aL * p + cp[(size_t)cc * 64];
        swv[w][lane] = p;
    }
    __syncthreads();
    if (w == 0) {   // combine 4 partials
        int q = (c + 3) >> 2;
        float run = 0.f;
        #pragma unroll
        for (int ww = 0; ww < 4; ++ww) {
            int lo = ww * q; if (lo > c) lo = c;
            int hi = lo + q; if (hi > c) hi = c;
            run = run * expf(-ex_n * (float)(CHUNK * (hi - lo))) + swv[ww][lane];
        }
        hst[lane] = run;
    }

    // ---- P1: Bu -> buf ----
    if (IN_X) {
        float g = expf(gamma_log[lane]);
        float bw = 0.f;
        #pragma unroll
        for (int h = 0; h < 64; ++h) bw += Bm[lane * 64 + h] * Win[h];
        bw *= g;
        for (int i = 0; i < 32; ++i) {
            int t = w * 32 + i;
            buf[t * 65 + lane] = xg[t] * bw;
        }
    } else {
        frag2 bfr[4][2];
        #pragma unroll
        for (int nt = 0; nt < 4; ++nt) {
            int n = nt * 16 + l15;
            float g = expf(gamma_log[n]);
            bfr[nt][0] = bfrag2(Bm, n, lq * 8,      g);
            bfr[nt][1] = bfrag2(Bm, n, 32 + lq * 8, g);
        }
        #pragma unroll
        for (int tt = 0; tt < 2; ++tt) {
            int tb = 2 * w + tt;
            frag2 a0 = aload2((const UT*)ug, tb * 16 + l15, lq * 8);
            frag2 a1 = aload2((const UT*)ug, tb * 16 + l15, 32 + lq * 8);
            #pragma unroll
            for (int nt = 0; nt < 4; ++nt) {
                f32x4 acc = {0.f, 0.f, 0.f, 0.f};
                acc = mfma3(a0, bfr[nt][0], acc);
                acc = mfma3(a1, bfr[nt][1], acc);
                #pragma unroll
                for (int r = 0; r < 4; ++r)
                    buf[(tb * 16 + lq * 4 + r) * 65 + nt * 16 + l15] = acc[r];
            }
        }
    }
    __syncthreads();

    // ---- P2a: local scan (init 0), write packed h to rows t+1 ----
    {
        float s = 0.f;
        for (int i = 0; i < 32; ++i) {
            int t = 32 * w + i;
            s = a_n * s + buf[t * 65 + lane];
            if (t + 1 < CHUNK) hpk[SWZ(t + 1, lane)] = pack2(s);
        }
        swv[w][lane] = s;
    }
    __syncthreads();

    // ---- P2b: fixup with incoming state ----
    // wave w owns rows [32w, 32w+32): direct write at 32w, RMW at 32w+1..32w+31.
    // Row 32(w+1) is owned by wave w+1's direct write — do NOT touch it here (was a race).
    {
        const float a32 = expf(-ex_n * 32.f);
        float inc = hst[lane];
        for (int ww = 0; ww < w; ++ww) inc = inc * a32 + swv[ww][lane];
        hpk[SWZ(32 * w, lane)] = pack2(inc);
        float qq = inc;
        #pragma unroll
        for (int i = 0; i < 31; ++i) {
            int r = 32 * w + 1 + i;
            qq *= a_n;
            hpk[SWZ(r, lane)] = pack2(unpk(hpk[SWZ(r, lane)]) + qq);
        }
    }
    __syncthreads();

    // ---- P3: y = C.h_prev + Dv*u, tanh -> th (f16, rows stride 72, reusing buf) ----
    f16* thb = (f16*)buf;
    {
        frag2 cfr[4][2];
        float dv[4], winj[4];
        #pragma unroll
        for (int nt = 0; nt < 4; ++nt) {
            int j = nt * 16 + l15;
            cfr[nt][0] = bfrag2(Cm, j, lq * 8,      1.f);
            cfr[nt][1] = bfrag2(Cm, j, 32 + lq * 8, 1.f);
            dv[nt] = Dv[j];
            winj[nt] = IN_X ? Win[j] : 0.f;
        }
        #pragma unroll
        for (int tt = 0; tt < 2; ++tt) {
            int tb = 2 * w + tt;
            int trow = tb * 16 + l15;
            // A-frags (hi & lo of packed h) from swizzled LDS
            frag2 afr[2];
            #pragma unroll
            for (int kk = 0; kk < 2; ++kk) {
                int kb = kk * 32 + lq * 8;
                int sw = (trow & 7) << 2;
                const unsigned* hw = hpk + trow * 64;
                uint4 w0 = *(const uint4*)(hw + ((kb)     ^ sw));
                uint4 w1 = *(const uint4*)(hw + ((kb + 4) ^ sw));
                afr[kk].hi[0]=hi_of(w0.x); afr[kk].hi[1]=hi_of(w0.y); afr[kk].hi[2]=hi_of(w0.z); afr[kk].hi[3]=hi_of(w0.w);
                afr[kk].hi[4]=hi_of(w1.x); afr[kk].hi[5]=hi_of(w1.y); afr[kk].hi[6]=hi_of(w1.z); afr[kk].hi[7]=hi_of(w1.w);
                afr[kk].lo[0]=lo_of(w0.x); afr[kk].lo[1]=lo_of(w0.y); afr[kk].lo[2]=lo_of(w0.z); afr[kk].lo[3]=lo_of(w0.w);
                afr[kk].lo[4]=lo_of(w1.x); afr[kk].lo[5]=lo_of(w1.y); afr[kk].lo[6]=lo_of(w1.z); afr[kk].lo[7]=lo_of(w1.w);
            }
            f32x4 acc[4];
            #pragma unroll
            for (int nt = 0; nt < 4; ++nt) {
                f32x4 a4 = {0.f, 0.f, 0.f, 0.f};
                a4 = mfma3(afr[0], cfr[nt][0], a4);
                a4 = mfma3(afr[1], cfr[nt][1], a4);
                acc[nt] = a4;
            }
            #pragma unroll
            for (int r = 0; r < 4; ++r) {
                int t = tb * 16 + lq * 4 + r;
                float xt = IN_X ? xg[t] : 0.f;
                #pragma unroll
                for (int nt = 0; nt < 4; ++nt) {
                    int j = nt * 16 + l15;
                    float uu = IN_X ? xt * winj[nt] : (float)ug[(size_t)t * 64 + j];
                    float y = acc[nt][r] + dv[nt] * uu;
                    thb[t * 72 + j] = (f16)(y * rsqrtf(1.f + y * y));
                }
            }
        }
    }
    // no barrier needed: P4 reads only rows written by the same wave in P3

    // ---- P4: out = Wlin.th + blin + u (+ optional .Wout reduce) ----
    {
        f16x8 wfr[4][2];
        float blj[4], winj[4], woj[4];
        #pragma unroll
        for (int nt = 0; nt < 4; ++nt) {
            int j = nt * 16 + l15;
            wfr[nt][0] = bfrag1(Wlin, j, lq * 8);
            wfr[nt][1] = bfrag1(Wlin, j, 32 + lq * 8);
            blj[nt] = blin[j];
            winj[nt] = IN_X ? Win[j] : 0.f;
            woj[nt] = OUT_FINAL ? Wout[j] : 0.f;
        }
        #pragma unroll
        for (int tt = 0; tt < 2; ++tt) {
            int tb = 2 * w + tt;
            f16x8 a0 = *(const f16x8*)(thb + (tb * 16 + l15) * 72 + lq * 8);
            f16x8 a1 = *(const f16x8*)(thb + (tb * 16 + l15) * 72 + 32 + lq * 8);
            f32x4 acc[4];
            #pragma unroll
            for (int nt = 0; nt < 4; ++nt) {
                f32x4 a4 = {0.f, 0.f, 0.f, 0.f};
                a4 = MFMA(a0, wfr[nt][0], a4);
                a4 = MFMA(a1, wfr[nt][1], a4);
                acc[nt] = a4;
            }
            #pragma unroll
            for (int r = 0; r < 4; ++r) {
                int t = tb * 16 + lq * 4 + r;
                float xt = IN_X ? xg[t] : 0.f;
                if (OUT_FINAL) {
                    float val = 0.f;
                    #pragma unroll
                    for (int nt = 0; nt < 4; ++nt) {
                        int j = nt * 16 + l15;
                        float uu = IN_X ? xt * winj[nt] : (float)ug[(size_t)t * 64 + j];
                        val += (acc[nt][r] + blj[nt] + uu) * woj[nt];
                    }
                    val += __shfl_xor(val, 1);
                    val += __shfl_xor(val, 2);
                    val += __shfl_xor(val, 4);
                    val += __shfl_xor(val, 8);
                    if (l15 == 0) out[(size_t)b * T_ + t0 + t] = val;
                } else {
                    #pragma unroll
                    for (int nt = 0; nt < 4; ++nt) {
                        int j = nt * 16 + l15;
                        float uu = IN_X ? xt * winj[nt] : (float)ug[(size_t)t * 64 + j];
                        ug[(size_t)t * 64 + j] = (UT)(acc[nt][r] + blj[nt] + uu);
                    }
                }
            }
        }
    }
}

// ---------- host ----------
template<typename UT>
static void run_all(const float* x, const float* Win,
                    const float* nu, const float* ga,
                    const float* Bm, const float* Cm,
                    const float* Dv, const float* Wl,
                    const float* bl, const float* Wo,
                    UT* hbuf, float* carry, float* out, hipStream_t stream)
{
    dim3 grid(B_ * NCH), blk256(256), blk64(64);
    for (int i = 0; i < DEPTH_; ++i) {
        const float *nui = nu + i * 64, *gai = ga + i * 64;
        const float *Bmi = Bm + i * 64 * 64, *Cmi = Cm + i * 64 * 64;
        const float *Dvi = Dv + i * 64, *Wli = Wl + i * 64 * 64, *bli = bl + i * 64;
        if (i == 0)
            carry_x<<<grid, blk64, 0, stream>>>(x, Win, nui, gai, Bmi, carry);
        else
            carry_mfma<UT><<<grid, blk256, 0, stream>>>(hbuf, nui, gai, Bmi, carry);
        if (i == 0)
            lru_mfma<1, 0, UT><<<grid, blk256, 0, stream>>>(x, hbuf, Win, nui, gai, Bmi, Cmi, Dvi, Wli, bli, Wo, carry, out);
        else if (i == DEPTH_ - 1)
            lru_mfma<0, 1, UT><<<grid, blk256, 0, stream>>>(x, hbuf, Win, nui, gai, Bmi, Cmi, Dvi, Wli, bli, Wo, carry, out);
        else
            lru_mfma<0, 0, UT><<<grid, blk256, 0, stream>>>(x, hbuf, Win, nui, gai, Bmi, Cmi, Dvi, Wli, bli, Wo, carry, out);
    }
}

extern "C" void kernel_launch(void* const* d_in, const int* in_sizes, int n_in,
                              void* d_out, int out_size, void* d_ws, size_t ws_size,
                              hipStream_t stream)
{
    const float* x   = (const float*)d_in[0];
    const float* Win = (const float*)d_in[1];
    const float* nu  = (const float*)d_in[2];
    const float* ga  = (const float*)d_in[3];
    const float* Bm  = (const float*)d_in[4];
    const float* Cm  = (const float*)d_in[5];
    const float* Dv  = (const float*)d_in[6];
    const float* Wl  = (const float*)d_in[7];
    const float* bl  = (const float*)d_in[8];
    const float* Wo  = (const float*)d_in[9];
    float* out = (float*)d_out;

    const size_t act = (size_t)B_ * T_ * H_;
    const size_t carry_bytes = (size_t)B_ * NCH * 64 * sizeof(float);

    if (ws_size >= act * sizeof(float) + carry_bytes) {
        float* hbuf  = (float*)d_ws;
        float* carry = (float*)((char*)d_ws + act * sizeof(float));
        run_all<float>(x, Win, nu, ga, Bm, Cm, Dv, Wl, bl, Wo, hbuf, carry, out, stream);
    } else {
        f16* hbuf = (f16*)d_ws;
        float* carry = (float*)((char*)d_ws + act * sizeof(f16));
        run_all<f16>(x, Win, nu, ga, Bm, Cm, Dv, Wl, bl, Wo, hbuf, carry, out, stream);
    }
}